// Round 10
// baseline (1174.944 us; speedup 1.0000x reference)
//
#include <hip/hip_runtime.h>
#include <hip/hip_bf16.h>

// Problem constants
#define B_   32
#define N_   3200          // H*W*IC
#define C_   20
#define A_   64
#define IA_  32
#define CA_  1280          // C_*A_
#define NTILE_ 32          // n's per votes block
#define NGRP_  100         // N_/NTILE_
#define RSLICE_ 80         // route slice-groups per b (4 waves each)
#define ROWS_  10          // n's per route wave
#define OC_ 128

typedef unsigned short u16;
typedef unsigned int   u32;

__device__ __forceinline__ u16 f2bf(float f) {
    union { float f; u32 u; } v; v.f = f;
    u32 r = v.u + 0x7FFFu + ((v.u >> 16) & 1u);   // RNE
    return (u16)(r >> 16);
}
__device__ __forceinline__ void unp(u32 u, float& lo, float& hi) {
    lo = __uint_as_float(u << 16);
    hi = __uint_as_float(u & 0xffff0000u);
}

// ---------------------------------------------------------------------------
// Kernel A: votes[b,n,o] = sum_i x[b,n,i]*W[n,i,o], bf16 store.
// Round-6/8 structure (UNCHANGED — measured best): 20 KB single-buffer LDS,
// T14 async-STAGE split (loads for n+1 issued into registers before
// compute(n); ds_write after the next barrier).
// ---------------------------------------------------------------------------
__global__ __launch_bounds__(256) void votes_kernel(
    const float* __restrict__ x,     // [B, N, IA]
    const float* __restrict__ W,     // [N, IA, CA]
    u16*   __restrict__ votes,       // [B, N, CA] bf16
    float* __restrict__ partial)     // [B, NGRP_, CA]
{
    __shared__ __align__(16) float xs[B_][IA_];     // 4 KB
    __shared__ __align__(16) float ws[IA_ * OC_];   // 16 KB

    const int t     = threadIdx.x;
    const int oc    = blockIdx.x % 10;
    const int g     = blockIdx.x / 10;       // 0..99
    const int n0    = g * NTILE_;
    const int obase = oc * OC_;

    const int ol = (t & 31) * 4;
    const int b0 = (t >> 5) * 4;
    const int xb = t >> 3;                   // x staging: source b row
    const int xi = (t & 7) * 4;              // x staging: atom quad
    const int wi = t >> 5;                   // W staging: base k row

    float S[4][4];
    #pragma unroll
    for (int jb = 0; jb < 4; ++jb)
        #pragma unroll
        for (int jo = 0; jo < 4; ++jo) S[jb][jo] = 0.f;

    // ---- prologue: load n0 into registers ----
    float4 rx, rw0, rw1, rw2, rw3;
    {
        const int n = n0;
        rx = *(const float4*)&x[((size_t)xb * N_ + n) * IA_ + xi];
        const float* wsrc = &W[((size_t)n * IA_ + wi) * CA_ + obase + ol];
        rw0 = *(const float4*)(wsrc);
        rw1 = *(const float4*)(wsrc + (size_t)8 * CA_);
        rw2 = *(const float4*)(wsrc + (size_t)16 * CA_);
        rw3 = *(const float4*)(wsrc + (size_t)24 * CA_);
    }

    for (int nn = 0; nn < NTILE_; ++nn) {
        const int n = n0 + nn;
        __syncthreads();                      // LDS free (prev compute done)
        *(float4*)&xs[xb][xi] = rx;
        *(float4*)&ws[0 * 1024 + t * 4] = rw0;
        *(float4*)&ws[1 * 1024 + t * 4] = rw1;
        *(float4*)&ws[2 * 1024 + t * 4] = rw2;
        *(float4*)&ws[3 * 1024 + t * 4] = rw3;
        __syncthreads();                      // staged data visible

        if (nn + 1 < NTILE_) {
            const int nx = n + 1;
            rx = *(const float4*)&x[((size_t)xb * N_ + nx) * IA_ + xi];
            const float* wsrc = &W[((size_t)nx * IA_ + wi) * CA_ + obase + ol];
            rw0 = *(const float4*)(wsrc);
            rw1 = *(const float4*)(wsrc + (size_t)8 * CA_);
            rw2 = *(const float4*)(wsrc + (size_t)16 * CA_);
            rw3 = *(const float4*)(wsrc + (size_t)24 * CA_);
        }

        float v[4][4];
        #pragma unroll
        for (int jb = 0; jb < 4; ++jb)
            #pragma unroll
            for (int jo = 0; jo < 4; ++jo) v[jb][jo] = 0.f;

        #pragma unroll
        for (int iq = 0; iq < 8; ++iq) {
            float4 xq[4], wq[4];
            #pragma unroll
            for (int j = 0; j < 4; ++j)
                xq[j] = *(const float4*)&xs[b0 + j][iq * 4];
            #pragma unroll
            for (int j = 0; j < 4; ++j)
                wq[j] = *(const float4*)&ws[(iq * 4 + j) * OC_ + ol];
            #pragma unroll
            for (int jb = 0; jb < 4; ++jb) {
                #pragma unroll
                for (int jo = 0; jo < 4; ++jo) {
                    v[jb][jo] += xq[jb].x * wq[0][jo];
                    v[jb][jo] += xq[jb].y * wq[1][jo];
                    v[jb][jo] += xq[jb].z * wq[2][jo];
                    v[jb][jo] += xq[jb].w * wq[3][jo];
                }
            }
        }
        #pragma unroll
        for (int jb = 0; jb < 4; ++jb) {
            ushort4 pk;
            pk.x = f2bf(v[jb][0]); pk.y = f2bf(v[jb][1]);
            pk.z = f2bf(v[jb][2]); pk.w = f2bf(v[jb][3]);
            S[jb][0] += v[jb][0]; S[jb][1] += v[jb][1];
            S[jb][2] += v[jb][2]; S[jb][3] += v[jb][3];
            *(ushort4*)&votes[((size_t)(b0 + jb) * N_ + n) * CA_ + obase + ol] = pk;
        }
    }
    #pragma unroll
    for (int jb = 0; jb < 4; ++jb) {
        float4 s4 = make_float4(S[jb][0], S[jb][1], S[jb][2], S[jb][3]);
        *(float4*)&partial[((size_t)(b0 + jb) * NGRP_ + g) * CA_ + obase + ol] = s4;
    }
}

// ---------------------------------------------------------------------------
// Kernel B: fused routing pass (round-8 inner loop UNCHANGED) + fused
// last-block reduction: the 80th block finishing for a given b reduces
// partial[b][0..79][o], adds bias, squashes (capsule == one wave: 64-lane
// butterfly) and writes dst[b] directly. rocPRIM-style fence/atomic pattern.
// route2: act_in=act1, dst=act2. route3: act_in=act2, dst=out.
// ---------------------------------------------------------------------------
template <int T>
__global__ __launch_bounds__(256) __attribute__((amdgpu_waves_per_eu(3)))
void route_kernel(
    const u16*  __restrict__ votes,      // [B,N,CA] bf16
    const float* __restrict__ act,       // [B,C,A]  (input activation)
    const float* __restrict__ logits_in, // [B,N,C] (T==3)
    float* __restrict__ logits_out,      // [B,N,C] (T==2)
    float* __restrict__ partial,         // [B,RSLICE_,CA]
    const float* __restrict__ bias,      // [C,A]
    float* __restrict__ dst,             // [B,C,A]  (output activation)
    int* __restrict__ ctr)               // [B_] zeroed counters
{
    __shared__ float red[4][CA_];        // 20 KB
    __shared__ int lastflag;
    const int t    = threadIdx.x;
    const int lane = t & 63;
    const int w    = t >> 6;
    const int b    = blockIdx.x / RSLICE_;
    const int sgrp = blockIdx.x % RSLICE_;
    const int slice = sgrp * 4 + w;      // 0..319, ROWS_ n's each
    const int c0   = lane >> 3;
    const bool has2 = lane < 32;
    const bool isL  = (lane & 7) == 0;
    const int off0 = lane * 8;
    const int off1 = off0 + 512;
    const int off2 = has2 ? off0 + 1024 : off0;

    float av0[8], av1[8], av2[8];
    {
        const float* ab = act + (size_t)b * CA_;
        #pragma unroll
        for (int j = 0; j < 2; ++j) {
            float4 f;
            f = *(const float4*)(ab + off0 + 4 * j);
            av0[4*j] = f.x; av0[4*j+1] = f.y; av0[4*j+2] = f.z; av0[4*j+3] = f.w;
            f = *(const float4*)(ab + off1 + 4 * j);
            av1[4*j] = f.x; av1[4*j+1] = f.y; av1[4*j+2] = f.z; av1[4*j+3] = f.w;
            f = *(const float4*)(ab + off2 + 4 * j);
            av2[4*j] = f.x; av2[4*j+1] = f.y; av2[4*j+2] = f.z; av2[4*j+3] = f.w;
        }
    }
    float ac0[8], ac1[8], ac2[8];
    #pragma unroll
    for (int j = 0; j < 8; ++j) { ac0[j] = 0.f; ac1[j] = 0.f; ac2[j] = 0.f; }

    const u16* vrow = votes + ((size_t)b * N_ + (size_t)slice * ROWS_) * CA_;
    uint4 qa0 = *(const uint4*)(vrow + off0);
    uint4 qa1 = *(const uint4*)(vrow + off1);
    uint4 qa2 = *(const uint4*)(vrow + off2);

    const float* lgp = (T == 3) ? (logits_in  + ((size_t)b * N_ + (size_t)slice * ROWS_) * C_) : nullptr;
    float*       lsp = (T == 2) ? (logits_out + ((size_t)b * N_ + (size_t)slice * ROWS_) * C_) : nullptr;

    float lf0 = 0.f, lf1 = 0.f, lf2 = 0.f;
    if (T == 3) {
        lf0 = lgp[c0]; lf1 = lgp[8 + c0];
        lf2 = has2 ? lgp[16 + c0] : 0.f;
    }

    for (int k = 0; k < ROWS_; ++k) {
        const u16* vnx = vrow + (size_t)((k < ROWS_ - 1) ? (k + 1) : k) * CA_;
        uint4 qb0 = *(const uint4*)(vnx + off0);
        uint4 qb1 = *(const uint4*)(vnx + off1);
        uint4 qb2 = *(const uint4*)(vnx + off2);
        float ln0 = 0.f, ln1 = 0.f, ln2 = 0.f;
        if (T == 3 && k < ROWS_ - 1) {
            ln0 = lgp[(k + 1) * C_ + c0];
            ln1 = lgp[(k + 1) * C_ + 8 + c0];
            ln2 = has2 ? lgp[(k + 1) * C_ + 16 + c0] : 0.f;
        }

        float v0[8], v1[8], v2[8];
        unp(qa0.x, v0[0], v0[1]); unp(qa0.y, v0[2], v0[3]);
        unp(qa0.z, v0[4], v0[5]); unp(qa0.w, v0[6], v0[7]);
        unp(qa1.x, v1[0], v1[1]); unp(qa1.y, v1[2], v1[3]);
        unp(qa1.z, v1[4], v1[5]); unp(qa1.w, v1[6], v1[7]);
        unp(qa2.x, v2[0], v2[1]); unp(qa2.y, v2[2], v2[3]);
        unp(qa2.z, v2[4], v2[5]); unp(qa2.w, v2[6], v2[7]);

        float d0 = 0.f, d1 = 0.f, d2 = 0.f;
        #pragma unroll
        for (int j = 0; j < 8; ++j) {
            d0 += v0[j] * av0[j];
            d1 += v1[j] * av1[j];
            d2 += v2[j] * av2[j];
        }
        #pragma unroll
        for (int s = 1; s <= 4; s <<= 1) {
            d0 += __shfl_xor(d0, s);
            d1 += __shfl_xor(d1, s);
            d2 += __shfl_xor(d2, s);
        }

        const float lg0 = d0 + lf0;
        const float lg1 = d1 + lf1;
        const float lg2 = d2 + lf2;

        if (T == 2 && isL) {
            lsp[k * C_ + c0]     = lg0;
            lsp[k * C_ + 8 + c0] = lg1;
            if (has2) lsp[k * C_ + 16 + c0] = lg2;
        }

        const float e0 = __expf(lg0);
        const float e1 = __expf(lg1);
        const float e2 = has2 ? __expf(lg2) : 0.f;
        float sm = e0 + e1 + e2;
        #pragma unroll
        for (int s = 8; s <= 32; s <<= 1) sm += __shfl_xor(sm, s);
        const float is = __builtin_amdgcn_rcpf(sm);
        const float r0 = e0 * is, r1 = e1 * is, r2 = e2 * is;

        #pragma unroll
        for (int j = 0; j < 8; ++j) {
            ac0[j] += r0 * v0[j];
            ac1[j] += r1 * v1[j];
            ac2[j] += r2 * v2[j];
        }
        qa0 = qb0; qa1 = qb1; qa2 = qb2;
        lf0 = ln0; lf1 = ln1; lf2 = ln2;
    }

    // ---- block reduce (4 waves) -> partial slice ----
    #pragma unroll
    for (int j = 0; j < 2; ++j) {
        *(float4*)&red[w][off0 + 4 * j] = make_float4(ac0[4*j], ac0[4*j+1], ac0[4*j+2], ac0[4*j+3]);
        *(float4*)&red[w][off1 + 4 * j] = make_float4(ac1[4*j], ac1[4*j+1], ac1[4*j+2], ac1[4*j+3]);
        if (has2)
            *(float4*)&red[w][off0 + 1024 + 4 * j] = make_float4(ac2[4*j], ac2[4*j+1], ac2[4*j+2], ac2[4*j+3]);
    }
    __syncthreads();
    float* pp = partial + ((size_t)b * RSLICE_ + sgrp) * CA_;
    for (int o = t; o < CA_; o += 256)
        pp[o] = red[0][o] + red[1][o] + red[2][o] + red[3][o];

    // ---- last-block-per-b: fused reduce + bias + squash -> dst[b] ----
    __threadfence();                       // release partial writes
    __syncthreads();
    if (t == 0) lastflag = atomicAdd(&ctr[b], 1);
    __syncthreads();
    if (lastflag == RSLICE_ - 1) {
        __threadfence();                   // acquire others' partial writes
        const float* pb = partial + (size_t)b * RSLICE_ * CA_;
        #pragma unroll
        for (int j = 0; j < 5; ++j) {
            const int o = j * 256 + t;     // capsule = 4j + (t>>6), atom = t&63
            float s = 0.f;
            for (int si = 0; si < RSLICE_; ++si)
                s += pb[(size_t)si * CA_ + o];
            const float p = s + bias[o];
            float sq = p * p;
            #pragma unroll
            for (int sh = 32; sh >= 1; sh >>= 1) sq += __shfl_xor(sq, sh);
            dst[(size_t)b * CA_ + o] = p * sqrtf(sq) / (1.f + sq);
        }
    }
}

// ---------------------------------------------------------------------------
// Reduce partials over S slices, add bias, squash. One block per (b,c).
// (Used only for iteration 1, after votes_kernel.)
// ---------------------------------------------------------------------------
__global__ __launch_bounds__(256) void reduce_squash(
    const float* __restrict__ partial,   // [B][S][CA_]
    int S, float scale,
    const float* __restrict__ bias,      // [C,A]
    float* __restrict__ dst)             // [B,C,A]
{
    __shared__ float red[4][A_];
    const int blk = blockIdx.x;          // 640
    const int b = blk / C_;
    const int c = blk % C_;
    const int t = threadIdx.x;
    const int a = t & 63;
    const int sc = t >> 6;

    const float* pp = partial + (size_t)b * S * CA_ + c * A_ + a;
    float s = 0.f;
    for (int si = sc; si < S; si += 4) s += pp[(size_t)si * CA_];
    red[sc][a] = s;
    __syncthreads();
    if (t < 64) {
        const float p = (red[0][a] + red[1][a] + red[2][a] + red[3][a]) * scale
                      + bias[c * A_ + a];
        float sq = p * p;
        #pragma unroll
        for (int sh = 32; sh >= 1; sh >>= 1) sq += __shfl_xor(sq, sh);
        dst[((size_t)b * C_ + c) * A_ + a] = p * sqrtf(sq) / (1.f + sq);
    }
}

// ---------------------------------------------------------------------------
extern "C" void kernel_launch(void* const* d_in, const int* in_sizes, int n_in,
                              void* d_out, int out_size, void* d_ws, size_t ws_size,
                              hipStream_t stream) {
    const float* x    = (const float*)d_in[0];
    const float* W    = (const float*)d_in[1];
    const float* bias = (const float*)d_in[2];
    float* out = (float*)d_out;

    // workspace layout (~287.1 MB)
    char* ws = (char*)d_ws;
    u16*   votes   = (u16*)ws;                                   // 262,144,000 B
    float* logits  = (float*)(ws + 262144000ull);                //   8,192,000 B
    float* partial = (float*)(ws + 262144000ull + 8192000ull);   //  16,384,000 B
    float* act1    = (float*)(ws + 286720000ull);                //     163,840 B
    int*   ctr     = (int*)  (ws + 286883840ull);                //         256 B
    float* act2    = (float*)(ws + 286884096ull);                //     163,840 B

    // zero the last-block counters (2 x 32 ints)
    hipMemsetAsync(ctr, 0, 256, stream);

    // iter 1: votes + uniform-route partial sums; squash with scale 1/20
    votes_kernel<<<NGRP_ * 10, 256, 0, stream>>>(x, W, votes, partial);
    reduce_squash<<<B_ * C_, 256, 0, stream>>>(partial, NGRP_, 1.f / (float)C_, bias, act1);

    // iter 2 (fused reduce+squash -> act2)
    route_kernel<2><<<B_ * RSLICE_, 256, 0, stream>>>(
        votes, act1, nullptr, logits, partial, bias, act2, ctr);

    // iter 3 (fused reduce+squash -> out; its logits update is dead)
    route_kernel<3><<<B_ * RSLICE_, 256, 0, stream>>>(
        votes, act2, logits, nullptr, partial, bias, out, ctr + 32);
}

// Round 11
// 296.137 us; speedup vs baseline: 3.9676x; 3.9676x over previous
//
#include <hip/hip_runtime.h>
#include <hip/hip_bf16.h>

// Problem constants
#define B_   32
#define N_   3200          // H*W*IC
#define C_   20
#define A_   64
#define IA_  32
#define CA_  1280          // C_*A_
#define NTILE_ 32          // n's per votes block
#define NGRP_  100         // N_/NTILE_
#define RSLICE_ 80         // route slice-groups per b (4 waves each -> 320 slices/b)
#define ROWS_  10          // n's per route wave (3200 / (RSLICE_*4))
#define OC_ 128

typedef unsigned short u16;
typedef unsigned int   u32;

__device__ __forceinline__ u16 f2bf(float f) {
    union { float f; u32 u; } v; v.f = f;
    u32 r = v.u + 0x7FFFu + ((v.u >> 16) & 1u);   // RNE
    return (u16)(r >> 16);
}
__device__ __forceinline__ void unp(u32 u, float& lo, float& hi) {
    lo = __uint_as_float(u << 16);
    hi = __uint_as_float(u & 0xffff0000u);
}

// ---------------------------------------------------------------------------
// Kernel A: votes[b,n,o] = sum_i x[b,n,i]*W[n,i,o], bf16 store.
// Round-6 structure (measured best): 20 KB single-buffer LDS, T14
// async-STAGE split (loads for n+1 issued into registers before compute(n);
// ds_write after the next barrier).
// ---------------------------------------------------------------------------
__global__ __launch_bounds__(256) void votes_kernel(
    const float* __restrict__ x,     // [B, N, IA]
    const float* __restrict__ W,     // [N, IA, CA]
    u16*   __restrict__ votes,       // [B, N, CA] bf16
    float* __restrict__ partial)     // [B, NGRP_, CA]
{
    __shared__ __align__(16) float xs[B_][IA_];     // 4 KB
    __shared__ __align__(16) float ws[IA_ * OC_];   // 16 KB

    const int t     = threadIdx.x;
    const int oc    = blockIdx.x % 10;
    const int g     = blockIdx.x / 10;       // 0..99
    const int n0    = g * NTILE_;
    const int obase = oc * OC_;

    const int ol = (t & 31) * 4;
    const int b0 = (t >> 5) * 4;
    const int xb = t >> 3;                   // x staging: source b row
    const int xi = (t & 7) * 4;              // x staging: atom quad
    const int wi = t >> 5;                   // W staging: base k row

    float S[4][4];
    #pragma unroll
    for (int jb = 0; jb < 4; ++jb)
        #pragma unroll
        for (int jo = 0; jo < 4; ++jo) S[jb][jo] = 0.f;

    // ---- prologue: load n0 into registers ----
    float4 rx, rw0, rw1, rw2, rw3;
    {
        const int n = n0;
        rx = *(const float4*)&x[((size_t)xb * N_ + n) * IA_ + xi];
        const float* wsrc = &W[((size_t)n * IA_ + wi) * CA_ + obase + ol];
        rw0 = *(const float4*)(wsrc);
        rw1 = *(const float4*)(wsrc + (size_t)8 * CA_);
        rw2 = *(const float4*)(wsrc + (size_t)16 * CA_);
        rw3 = *(const float4*)(wsrc + (size_t)24 * CA_);
    }

    for (int nn = 0; nn < NTILE_; ++nn) {
        const int n = n0 + nn;
        __syncthreads();                      // LDS free (prev compute done)
        *(float4*)&xs[xb][xi] = rx;
        *(float4*)&ws[0 * 1024 + t * 4] = rw0;
        *(float4*)&ws[1 * 1024 + t * 4] = rw1;
        *(float4*)&ws[2 * 1024 + t * 4] = rw2;
        *(float4*)&ws[3 * 1024 + t * 4] = rw3;
        __syncthreads();                      // staged data visible

        if (nn + 1 < NTILE_) {
            const int nx = n + 1;
            rx = *(const float4*)&x[((size_t)xb * N_ + nx) * IA_ + xi];
            const float* wsrc = &W[((size_t)nx * IA_ + wi) * CA_ + obase + ol];
            rw0 = *(const float4*)(wsrc);
            rw1 = *(const float4*)(wsrc + (size_t)8 * CA_);
            rw2 = *(const float4*)(wsrc + (size_t)16 * CA_);
            rw3 = *(const float4*)(wsrc + (size_t)24 * CA_);
        }

        float v[4][4];
        #pragma unroll
        for (int jb = 0; jb < 4; ++jb)
            #pragma unroll
            for (int jo = 0; jo < 4; ++jo) v[jb][jo] = 0.f;

        #pragma unroll
        for (int iq = 0; iq < 8; ++iq) {
            float4 xq[4], wq[4];
            #pragma unroll
            for (int j = 0; j < 4; ++j)
                xq[j] = *(const float4*)&xs[b0 + j][iq * 4];
            #pragma unroll
            for (int j = 0; j < 4; ++j)
                wq[j] = *(const float4*)&ws[(iq * 4 + j) * OC_ + ol];
            #pragma unroll
            for (int jb = 0; jb < 4; ++jb) {
                #pragma unroll
                for (int jo = 0; jo < 4; ++jo) {
                    v[jb][jo] += xq[jb].x * wq[0][jo];
                    v[jb][jo] += xq[jb].y * wq[1][jo];
                    v[jb][jo] += xq[jb].z * wq[2][jo];
                    v[jb][jo] += xq[jb].w * wq[3][jo];
                }
            }
        }
        #pragma unroll
        for (int jb = 0; jb < 4; ++jb) {
            ushort4 pk;
            pk.x = f2bf(v[jb][0]); pk.y = f2bf(v[jb][1]);
            pk.z = f2bf(v[jb][2]); pk.w = f2bf(v[jb][3]);
            S[jb][0] += v[jb][0]; S[jb][1] += v[jb][1];
            S[jb][2] += v[jb][2]; S[jb][3] += v[jb][3];
            *(ushort4*)&votes[((size_t)(b0 + jb) * N_ + n) * CA_ + obase + ol] = pk;
        }
    }
    #pragma unroll
    for (int jb = 0; jb < 4; ++jb) {
        float4 s4 = make_float4(S[jb][0], S[jb][1], S[jb][2], S[jb][3]);
        *(float4*)&partial[((size_t)(b0 + jb) * NGRP_ + g) * CA_ + obase + ol] = s4;
    }
}

// ---------------------------------------------------------------------------
// Kernel B: fused routing pass, flat-chunk layout (coalesced votes reads).
// Round-8 version (measured best): 1-deep prefetch, ROWS_=10 per wave,
// grid 2560 blocks. No fences, no cross-block atomics (round-10 lesson:
// device-scope fences serialize the non-coherent per-XCD L2s).
// ---------------------------------------------------------------------------
template <int T>
__global__ __launch_bounds__(256) __attribute__((amdgpu_waves_per_eu(3)))
void route_kernel(
    const u16*  __restrict__ votes,      // [B,N,CA] bf16
    const float* __restrict__ act,       // [B,C,A]
    const float* __restrict__ logits_in, // [B,N,C] (T==3)
    float* __restrict__ logits_out,      // [B,N,C] (T==2)
    float* __restrict__ partial)         // [B,RSLICE_,CA]
{
    __shared__ float red[4][CA_];        // 20 KB
    const int t    = threadIdx.x;
    const int lane = t & 63;
    const int w    = t >> 6;
    const int b    = blockIdx.x / RSLICE_;
    const int sgrp = blockIdx.x % RSLICE_;
    const int slice = sgrp * 4 + w;      // 0..319, ROWS_ n's each
    const int c0   = lane >> 3;
    const bool has2 = lane < 32;
    const bool isL  = (lane & 7) == 0;
    const int off0 = lane * 8;
    const int off1 = off0 + 512;
    const int off2 = has2 ? off0 + 1024 : off0;

    float av0[8], av1[8], av2[8];
    {
        const float* ab = act + (size_t)b * CA_;
        #pragma unroll
        for (int j = 0; j < 2; ++j) {
            float4 f;
            f = *(const float4*)(ab + off0 + 4 * j);
            av0[4*j] = f.x; av0[4*j+1] = f.y; av0[4*j+2] = f.z; av0[4*j+3] = f.w;
            f = *(const float4*)(ab + off1 + 4 * j);
            av1[4*j] = f.x; av1[4*j+1] = f.y; av1[4*j+2] = f.z; av1[4*j+3] = f.w;
            f = *(const float4*)(ab + off2 + 4 * j);
            av2[4*j] = f.x; av2[4*j+1] = f.y; av2[4*j+2] = f.z; av2[4*j+3] = f.w;
        }
    }
    float ac0[8], ac1[8], ac2[8];
    #pragma unroll
    for (int j = 0; j < 8; ++j) { ac0[j] = 0.f; ac1[j] = 0.f; ac2[j] = 0.f; }

    const u16* vrow = votes + ((size_t)b * N_ + (size_t)slice * ROWS_) * CA_;
    uint4 qa0 = *(const uint4*)(vrow + off0);
    uint4 qa1 = *(const uint4*)(vrow + off1);
    uint4 qa2 = *(const uint4*)(vrow + off2);

    const float* lgp = (T == 3) ? (logits_in  + ((size_t)b * N_ + (size_t)slice * ROWS_) * C_) : nullptr;
    float*       lsp = (T == 2) ? (logits_out + ((size_t)b * N_ + (size_t)slice * ROWS_) * C_) : nullptr;

    float lf0 = 0.f, lf1 = 0.f, lf2 = 0.f;
    if (T == 3) {
        lf0 = lgp[c0]; lf1 = lgp[8 + c0];
        lf2 = has2 ? lgp[16 + c0] : 0.f;
    }

    for (int k = 0; k < ROWS_; ++k) {
        const u16* vnx = vrow + (size_t)((k < ROWS_ - 1) ? (k + 1) : k) * CA_;
        uint4 qb0 = *(const uint4*)(vnx + off0);
        uint4 qb1 = *(const uint4*)(vnx + off1);
        uint4 qb2 = *(const uint4*)(vnx + off2);
        float ln0 = 0.f, ln1 = 0.f, ln2 = 0.f;
        if (T == 3 && k < ROWS_ - 1) {
            ln0 = lgp[(k + 1) * C_ + c0];
            ln1 = lgp[(k + 1) * C_ + 8 + c0];
            ln2 = has2 ? lgp[(k + 1) * C_ + 16 + c0] : 0.f;
        }

        float v0[8], v1[8], v2[8];
        unp(qa0.x, v0[0], v0[1]); unp(qa0.y, v0[2], v0[3]);
        unp(qa0.z, v0[4], v0[5]); unp(qa0.w, v0[6], v0[7]);
        unp(qa1.x, v1[0], v1[1]); unp(qa1.y, v1[2], v1[3]);
        unp(qa1.z, v1[4], v1[5]); unp(qa1.w, v1[6], v1[7]);
        unp(qa2.x, v2[0], v2[1]); unp(qa2.y, v2[2], v2[3]);
        unp(qa2.z, v2[4], v2[5]); unp(qa2.w, v2[6], v2[7]);

        float d0 = 0.f, d1 = 0.f, d2 = 0.f;
        #pragma unroll
        for (int j = 0; j < 8; ++j) {
            d0 += v0[j] * av0[j];
            d1 += v1[j] * av1[j];
            d2 += v2[j] * av2[j];
        }
        #pragma unroll
        for (int s = 1; s <= 4; s <<= 1) {
            d0 += __shfl_xor(d0, s);
            d1 += __shfl_xor(d1, s);
            d2 += __shfl_xor(d2, s);
        }

        const float lg0 = d0 + lf0;
        const float lg1 = d1 + lf1;
        const float lg2 = d2 + lf2;

        if (T == 2 && isL) {
            lsp[k * C_ + c0]     = lg0;
            lsp[k * C_ + 8 + c0] = lg1;
            if (has2) lsp[k * C_ + 16 + c0] = lg2;
        }

        const float e0 = __expf(lg0);
        const float e1 = __expf(lg1);
        const float e2 = has2 ? __expf(lg2) : 0.f;
        float sm = e0 + e1 + e2;
        #pragma unroll
        for (int s = 8; s <= 32; s <<= 1) sm += __shfl_xor(sm, s);
        const float is = __builtin_amdgcn_rcpf(sm);
        const float r0 = e0 * is, r1 = e1 * is, r2 = e2 * is;

        #pragma unroll
        for (int j = 0; j < 8; ++j) {
            ac0[j] += r0 * v0[j];
            ac1[j] += r1 * v1[j];
            ac2[j] += r2 * v2[j];
        }
        qa0 = qb0; qa1 = qb1; qa2 = qb2;
        lf0 = ln0; lf1 = ln1; lf2 = ln2;
    }

    #pragma unroll
    for (int j = 0; j < 2; ++j) {
        *(float4*)&red[w][off0 + 4 * j] = make_float4(ac0[4*j], ac0[4*j+1], ac0[4*j+2], ac0[4*j+3]);
        *(float4*)&red[w][off1 + 4 * j] = make_float4(ac1[4*j], ac1[4*j+1], ac1[4*j+2], ac1[4*j+3]);
        if (has2)
            *(float4*)&red[w][off0 + 1024 + 4 * j] = make_float4(ac2[4*j], ac2[4*j+1], ac2[4*j+2], ac2[4*j+3]);
    }
    __syncthreads();
    float* pp = partial + ((size_t)b * RSLICE_ + sgrp) * CA_;
    for (int o = t; o < CA_; o += 256)
        pp[o] = red[0][o] + red[1][o] + red[2][o] + red[3][o];
}

// ---------------------------------------------------------------------------
// Reduce partials over S slices, add bias, squash. One block per (b,c).
// ---------------------------------------------------------------------------
__global__ __launch_bounds__(256) void reduce_squash(
    const float* __restrict__ partial,   // [B][S][CA_]
    int S, float scale,
    const float* __restrict__ bias,      // [C,A]
    float* __restrict__ dst)             // [B,C,A]
{
    __shared__ float red[4][A_];
    const int blk = blockIdx.x;          // 640
    const int b = blk / C_;
    const int c = blk % C_;
    const int t = threadIdx.x;
    const int a = t & 63;
    const int sc = t >> 6;

    const float* pp = partial + (size_t)b * S * CA_ + c * A_ + a;
    float s = 0.f;
    for (int si = sc; si < S; si += 4) s += pp[(size_t)si * CA_];
    red[sc][a] = s;
    __syncthreads();
    if (t < 64) {
        const float p = (red[0][a] + red[1][a] + red[2][a] + red[3][a]) * scale
                      + bias[c * A_ + a];
        float sq = p * p;
        #pragma unroll
        for (int sh = 32; sh >= 1; sh >>= 1) sq += __shfl_xor(sq, sh);
        dst[((size_t)b * C_ + c) * A_ + a] = p * sqrtf(sq) / (1.f + sq);
    }
}

// ---------------------------------------------------------------------------
extern "C" void kernel_launch(void* const* d_in, const int* in_sizes, int n_in,
                              void* d_out, int out_size, void* d_ws, size_t ws_size,
                              hipStream_t stream) {
    const float* x    = (const float*)d_in[0];
    const float* W    = (const float*)d_in[1];
    const float* bias = (const float*)d_in[2];
    float* out = (float*)d_out;

    // workspace layout (~287 MB)
    char* ws = (char*)d_ws;
    u16*   votes   = (u16*)ws;                                   // 262,144,000 B
    float* logits  = (float*)(ws + 262144000ull);                //   8,192,000 B
    float* partial = (float*)(ws + 262144000ull + 8192000ull);   //  16,384,000 B
    float* act     = (float*)(ws + 262144000ull + 8192000ull + 16384000ull);

    // iter 1: votes + uniform-route partial sums; squash with scale 1/20
    votes_kernel<<<NGRP_ * 10, 256, 0, stream>>>(x, W, votes, partial);
    reduce_squash<<<B_ * C_, 256, 0, stream>>>(partial, NGRP_, 1.f / (float)C_, bias, act);

    // iter 2
    route_kernel<2><<<B_ * RSLICE_, 256, 0, stream>>>(votes, act, nullptr, logits, partial);
    reduce_squash<<<B_ * C_, 256, 0, stream>>>(partial, RSLICE_, 1.f, bias, act);

    // iter 3 (its logits update is dead in the reference)
    route_kernel<3><<<B_ * RSLICE_, 256, 0, stream>>>(votes, act, logits, nullptr, partial);
    reduce_squash<<<B_ * C_, 256, 0, stream>>>(partial, RSLICE_, 1.f, bias, out);
}